// Round 4
// baseline (749.094 us; speedup 1.0000x reference)
//
#include <hip/hip_runtime.h>

#define T_N 1024
#define H_N 128
#define CH   64
#define NCH (T_N / CH)     // 16
#define WPAD 136           // shorts per row of bf16 [n][k] weight tiles (272B rows: 2-way banks only)
#define TPAD 68            // floats per row of pT [h][t] (272B rows: 16B aligned, 2-way banks only)

typedef __attribute__((ext_vector_type(8))) short bf16x8;
typedef __attribute__((ext_vector_type(4))) float f32x4;

__device__ __forceinline__ short f2bf_rne(float f) {
    union { float f; unsigned int i; } v; v.f = f;
    unsigned int r = v.i + 0x7FFFu + ((v.i >> 16) & 1u);
    return (short)(r >> 16);
}
__device__ __forceinline__ float tanh_fast(float x) {
    return 1.0f - 2.0f / (__expf(2.0f * x) + 1.0f);
}

// One block per batch row, 2 waves.
// wave0: barrier-free recurrence. Depth-1/2 MFMA (NO deep C-chains: round-1/2
//   showed chained-C MFMA latency ~130cyc is the dominant stall; round-0's
//   depth-1 + VALU-reduce was measured-good). K=128 split into 2 chains of 2
//   per tile, links separated by 16 independent MFMAs.
//   State layout is sigma-PERMUTED so each lane's two output columns pack into
//   one v_cvt_pk_bf16_f32 + one ds_write_b32: sst16[32q+2l+b] = state[32q+16b+l].
//   Weight frags are gathered with the inverse permutation once at startup, so
//   MFMA math is unchanged.
//   wave0 runs at setprio(1) permanently: it IS the critical path; wave1's
//   chunk GEMM has 64 steps of slack and should yield issue slots.
// wave1: computes chunk c+1's input projection while wave0 steps chunk c.
//   One barrier per 64 steps.
__global__ __launch_bounds__(128, 1) void k_fused(const float* __restrict__ x,
                                                  const float* __restrict__ w,
                                                  const float* __restrict__ wst,
                                                  const float* __restrict__ bias,
                                                  float* __restrict__ out) {
    __shared__ __align__(16) short wT[H_N * WPAD];     // input-proj w, bf16 [n][k]
    __shared__ __align__(16) float pT[2][H_N * TPAD];  // proj chunk [h][t] dbuf; wsT staging at startup
    __shared__ __align__(16) unsigned int sst32[64];   // packed state, sigma layout

    const int tid  = threadIdx.x;
    const int wv   = tid >> 6;
    const int lane = tid & 63;
    const int l = lane & 15;
    const int q = lane >> 4;
    const int r = blockIdx.x;
    const float* xrow = x + (size_t)r * T_N * H_N;
    const f32x4 zero4 = (f32x4){0.f, 0.f, 0.f, 0.f};

    // ---- stage wst -> bf16 [n][k] through pT[0]'s memory (exactly fits) ----
    short* wsTs = reinterpret_cast<short*>(&pT[0][0]);
    for (int e = tid * 4; e < H_N * H_N; e += 512) {
        int k = e >> 7, n = e & 127;
        float4 a4 = *reinterpret_cast<const float4*>(wst + e);
        wsTs[(n + 0) * WPAD + k] = f2bf_rne(a4.x);
        wsTs[(n + 1) * WPAD + k] = f2bf_rne(a4.y);
        wsTs[(n + 2) * WPAD + k] = f2bf_rne(a4.z);
        wsTs[(n + 3) * WPAD + k] = f2bf_rne(a4.w);
    }
    // ---- stage w -> bf16 [n][k] LDS ----
    for (int e = tid * 4; e < H_N * H_N; e += 512) {
        int k = e >> 7, n = e & 127;
        float4 a4 = *reinterpret_cast<const float4*>(w + e);
        wT[(n + 0) * WPAD + k] = f2bf_rne(a4.x);
        wT[(n + 1) * WPAD + k] = f2bf_rne(a4.y);
        wT[(n + 2) * WPAD + k] = f2bf_rne(a4.z);
        wT[(n + 3) * WPAD + k] = f2bf_rne(a4.w);
    }

    float bv[8];
    #pragma unroll
    for (int nt = 0; nt < 8; ++nt) bv[nt] = bias[nt * 16 + l];

    __syncthreads();

    // ---- chunk proj GEMM (wave1): proj rows [cc*64 .. +63] -> buf [h][t] f32 ----
    auto do_chunk = [&](int cc, float* buf) {
        const float* xc = xrow + (size_t)cc * CH * H_N + (size_t)l * H_N + q * 8;
        #pragma unroll 1
        for (int tile = 0; tile < 4; ++tile) {
            const float* xp = xc + (size_t)tile * 16 * H_N;
            float4 u[8];
            #pragma unroll
            for (int ks = 0; ks < 4; ++ks) {
                u[2 * ks]     = *reinterpret_cast<const float4*>(xp + ks * 32);
                u[2 * ks + 1] = *reinterpret_cast<const float4*>(xp + ks * 32 + 4);
            }
            bf16x8 ax[4];
            #pragma unroll
            for (int ks = 0; ks < 4; ++ks) {
                float4 u0 = u[2 * ks], u1 = u[2 * ks + 1];
                bf16x8 f;
                f[0] = f2bf_rne(u0.x); f[1] = f2bf_rne(u0.y);
                f[2] = f2bf_rne(u0.z); f[3] = f2bf_rne(u0.w);
                f[4] = f2bf_rne(u1.x); f[5] = f2bf_rne(u1.y);
                f[6] = f2bf_rne(u1.z); f[7] = f2bf_rne(u1.w);
                ax[ks] = f;
            }
            // latency fully hidden behind wave0's 64 steps -> chain order is fine here
            #pragma unroll
            for (int nt = 0; nt < 8; ++nt) {
                f32x4 acc;
                #pragma unroll
                for (int ks = 0; ks < 4; ++ks) {
                    bf16x8 bw = *reinterpret_cast<const bf16x8*>(
                        &wT[(nt * 16 + l) * WPAD + ks * 32 + q * 8]);
                    acc = __builtin_amdgcn_mfma_f32_16x16x32_bf16(
                        ax[ks], bw, ks == 0 ? zero4 : acc, 0, 0, 0);
                }
                f32x4 o = (f32x4){acc[0] + bv[nt], acc[1] + bv[nt],
                                  acc[2] + bv[nt], acc[3] + bv[nt]};
                *reinterpret_cast<f32x4*>(
                    &buf[(nt * 16 + l) * TPAD + tile * 16 + 4 * q]) = o;
            }
        }
    };

    // ---- state-weight B-frags, sigma-gathered (wave0 only, once) ----
    // A-frag element (ks,q,i) reads sst16[32ks+8q+i] -> col 32ks+16(i&1)+4q+(i>>1),
    // so wf element i must be Wst[32ks+16(i&1)+4q+(i>>1)][16nt+l].
    bf16x8 wf[8][4];
    if (wv == 0) {
        __builtin_amdgcn_s_setprio(1);   // wave0 = critical path, keep at prio 1
        #pragma unroll
        for (int nt = 0; nt < 8; ++nt)
            #pragma unroll
            for (int ks = 0; ks < 4; ++ks) {
                const short* rp = &wsTs[(16 * nt + l) * WPAD + 32 * ks + 4 * q];
                short4 lo = *reinterpret_cast<const short4*>(rp);
                short4 hi = *reinterpret_cast<const short4*>(rp + 16);
                wf[nt][ks] = (bf16x8){lo.x, hi.x, lo.y, hi.y,
                                      lo.z, hi.z, lo.w, hi.w};
            }
    } else {
        do_chunk(0, &pT[1][0]);   // chunk 0 -> pT[1] (pT[0] still holds wsT)
    }
    __syncthreads();

    float y0 = 0.f, y1 = 0.f;
    const int row0 = (32 * q + l) * TPAD;
    const int row1 = (32 * q + 16 + l) * TPAD;
    const short* sst16 = reinterpret_cast<const short*>(sst32);

    #pragma unroll 1
    for (int c = 0; c < NCH; ++c) {
        if (wv == 0) {
            // chunk cc lives in pT[(cc+1)&1]
            float* pc = &pT[(c + 1) & 1][0];
            int ts = 0;
            if (c == 0) {
                // state0 = tanh(proj[0]); each lane writes its own packed dword
                float s0 = tanh_fast(pc[row0]);
                float s1 = tanh_fast(pc[row1]);
                unsigned int pk;
                asm("v_cvt_pk_bf16_f32 %0, %1, %2" : "=v"(pk) : "v"(s0), "v"(s1));
                sst32[lane] = pk;
                ts = 1;
            }
            float p0 = pc[row0 + ts];
            float p1 = pc[row1 + ts];
            #pragma unroll 1
            for (int t = ts; t < CH; ++t) {
                // A-frags: broadcast within q-group, conflict-free
                bf16x8 a[4];
                #pragma unroll
                for (int ks = 0; ks < 4; ++ks)
                    a[ks] = *reinterpret_cast<const bf16x8*>(&sst16[32 * ks + 8 * q]);

                int tn = (t + 1 < CH) ? t + 1 : t;
                float np0 = pc[row0 + tn];
                float np1 = pc[row1 + tn];

                // 16 chains of depth 2; links separated by 16 independent MFMAs
                f32x4 acc[8][2];
                #pragma unroll
                for (int nt = 0; nt < 8; ++nt)
                    acc[nt][0] = __builtin_amdgcn_mfma_f32_16x16x32_bf16(
                        a[0], wf[nt][0], zero4, 0, 0, 0);
                #pragma unroll
                for (int nt = 0; nt < 8; ++nt)
                    acc[nt][1] = __builtin_amdgcn_mfma_f32_16x16x32_bf16(
                        a[2], wf[nt][2], zero4, 0, 0, 0);
                __builtin_amdgcn_sched_barrier(0);
                #pragma unroll
                for (int nt = 0; nt < 8; ++nt)
                    acc[nt][0] = __builtin_amdgcn_mfma_f32_16x16x32_bf16(
                        a[1], wf[nt][1], acc[nt][0], 0, 0, 0);
                #pragma unroll
                for (int nt = 0; nt < 8; ++nt)
                    acc[nt][1] = __builtin_amdgcn_mfma_f32_16x16x32_bf16(
                        a[3], wf[nt][3], acc[nt][1], 0, 0, 0);

                // lane (q,l) owns tiles 2q (col 32q+l) and 2q+1 (col 32q+16+l)
                float c00 = (q == 0) ? acc[0][0][0] : (q == 1) ? acc[2][0][0]
                          : (q == 2) ? acc[4][0][0] : acc[6][0][0];
                float c01 = (q == 0) ? acc[0][1][0] : (q == 1) ? acc[2][1][0]
                          : (q == 2) ? acc[4][1][0] : acc[6][1][0];
                float c10 = (q == 0) ? acc[1][0][0] : (q == 1) ? acc[3][0][0]
                          : (q == 2) ? acc[5][0][0] : acc[7][0][0];
                float c11 = (q == 0) ? acc[1][1][0] : (q == 1) ? acc[3][1][0]
                          : (q == 2) ? acc[5][1][0] : acc[7][1][0];
                y0 = tanh_fast(p0 + (c00 + c01));
                y1 = tanh_fast(p1 + (c10 + c11));
                unsigned int pk;
                asm("v_cvt_pk_bf16_f32 %0, %1, %2" : "=v"(pk) : "v"(y0), "v"(y1));
                sst32[lane] = pk;
                p0 = np0; p1 = np1;
                // no barrier: single-wave recurrence, DS ops in-order per wave
            }
        } else if (c + 1 < NCH) {
            do_chunk(c + 1, &pT[c & 1][0]);
        }
        __syncthreads();   // chunk handoff (1 barrier / 64 steps)
    }

    if (wv == 0) {
        out[r * H_N + 32 * q + l]      = y0;
        out[r * H_N + 32 * q + 16 + l] = y1;
    }
}

extern "C" void kernel_launch(void* const* d_in, const int* in_sizes, int n_in,
                              void* d_out, int out_size, void* d_ws, size_t ws_size,
                              hipStream_t stream) {
    const float* x    = (const float*)d_in[0];  // [B][T][D] fp32
    const float* w    = (const float*)d_in[1];  // [D][H]    fp32
    const float* wst  = (const float*)d_in[2];  // [H][H]    fp32
    const float* bias = (const float*)d_in[3];  // [H]       fp32
    float* out = (float*)d_out;                 // [B][H]    fp32

    k_fused<<<256, 128, 0, stream>>>(x, w, wst, bias, out);
}

// Round 5
// 698.570 us; speedup vs baseline: 1.0723x; 1.0723x over previous
//
#include <hip/hip_runtime.h>

#define T_N 1024
#define H_N 128
#define CH   64
#define NCH (T_N / CH)     // 16
#define WPAD 136           // shorts per row of bf16 weight tiles
#define PPAD 68            // floats per row of pT

typedef __attribute__((ext_vector_type(8))) short bf16x8;
typedef __attribute__((ext_vector_type(4))) float f32x4;

__device__ __forceinline__ short f2bf_rne(float f) {
    union { float f; unsigned int i; } v; v.f = f;
    unsigned int r = v.i + 0x7FFFu + ((v.i >> 16) & 1u);
    return (short)(r >> 16);
}
__device__ __forceinline__ float tanh_fast(float x) {
    return 1.0f - 2.0f / (__expf(2.0f * x) + 1.0f);
}

// TWO batch rows per block (grid 128), round-0 4-wave structure.
// Rounds 1-4 showed the single-wave redesign has a ~500ns/step floor (serial
// issue on one SIMD); round-0's 4-wave split (324ns/step) is the best base.
// Its step is mostly LATENCY (ds_read ~120cy + MFMA lat + tanh chain), with
// only ~150cy of issue per wave -> interleave a SECOND independent recurrence
// (row r1) into the same step loop: both rows' state reads issued together
// (latencies overlap), row B's MFMA/tanh fill row A's stall slots. Same
// barrier, shared weights. ~2x throughput at ~1.2-1.4x step time.
__global__ __launch_bounds__(256, 1) void k_fused(const float* __restrict__ x,
                                                  const float* __restrict__ w,
                                                  const float* __restrict__ wst,
                                                  const float* __restrict__ bias,
                                                  float* __restrict__ out) {
    __shared__ __align__(16) short wT[H_N * WPAD];    // input-proj w, bf16 [n][k]
    __shared__ __align__(16) float pTA[H_N * PPAD];   // row A proj chunk [h][t]; wsT staging at startup
    __shared__ __align__(16) float pTB[H_N * PPAD];   // row B proj chunk [h][t]
    __shared__ __align__(16) short sstA[2][H_N];      // row A state dbuf, bf16
    __shared__ __align__(16) short sstB[2][H_N];      // row B state dbuf, bf16

    const int tid  = threadIdx.x;
    const int wv   = tid >> 6;       // wave: GEMM t-rows 16wv..+15; step cols 32wv+l, 32wv+16+l
    const int lane = tid & 63;
    const int l = lane & 15;
    const int q = lane >> 4;
    const int r0 = blockIdx.x * 2;
    const int r1 = r0 + 1;
    const float* xrowA = x + (size_t)r0 * T_N * H_N;
    const float* xrowB = x + (size_t)r1 * T_N * H_N;
    const f32x4 zero4 = (f32x4){0.f, 0.f, 0.f, 0.f};

    // ---- VGPR staging: chunk 0's x rows for this lane, BOTH rows ----
    const float* xlaneA = xrowA + (size_t)(wv * 16 + l) * H_N + q * 8;
    const float* xlaneB = xrowB + (size_t)(wv * 16 + l) * H_N + q * 8;
    float4 xstA[8], xstB[8];   // [ks][half]
    #pragma unroll
    for (int ks = 0; ks < 4; ++ks) {
        xstA[ks * 2 + 0] = *reinterpret_cast<const float4*>(xlaneA + ks * 32);
        xstA[ks * 2 + 1] = *reinterpret_cast<const float4*>(xlaneA + ks * 32 + 4);
        xstB[ks * 2 + 0] = *reinterpret_cast<const float4*>(xlaneB + ks * 32);
        xstB[ks * 2 + 1] = *reinterpret_cast<const float4*>(xlaneB + ks * 32 + 4);
    }

    // ---- stage wst (bf16 [n][k]) through pTA's memory ----
    short* wsTs = reinterpret_cast<short*>(pTA);
    for (int e = tid * 4; e < H_N * H_N; e += 1024) {
        int k = e >> 7, n = e & 127;
        float4 a4 = *reinterpret_cast<const float4*>(wst + e);
        wsTs[(n + 0) * WPAD + k] = f2bf_rne(a4.x);
        wsTs[(n + 1) * WPAD + k] = f2bf_rne(a4.y);
        wsTs[(n + 2) * WPAD + k] = f2bf_rne(a4.z);
        wsTs[(n + 3) * WPAD + k] = f2bf_rne(a4.w);
    }
    __syncthreads();

    bf16x8 wf[2][4];   // state-W B-frags for this wave's nt pair (shared by both rows)
    #pragma unroll
    for (int b = 0; b < 2; ++b)
        #pragma unroll
        for (int ks = 0; ks < 4; ++ks)
            wf[b][ks] = *reinterpret_cast<const bf16x8*>(
                &wsTs[(16 * (2 * wv + b) + l) * WPAD + ks * 32 + q * 8]);
    __syncthreads();

    // ---- input-proj weights -> bf16 [n][k] LDS ----
    for (int e = tid * 4; e < H_N * H_N; e += 1024) {
        int k = e >> 7, n = e & 127;
        float4 a4 = *reinterpret_cast<const float4*>(w + e);
        wT[(n + 0) * WPAD + k] = f2bf_rne(a4.x);
        wT[(n + 1) * WPAD + k] = f2bf_rne(a4.y);
        wT[(n + 2) * WPAD + k] = f2bf_rne(a4.z);
        wT[(n + 3) * WPAD + k] = f2bf_rne(a4.w);
    }

    float bv[8];
    #pragma unroll
    for (int nt = 0; nt < 8; ++nt) bv[nt] = bias[nt * 16 + l];

    int par = 0;
    float yA0 = 0.f, yA1 = 0.f, yB0 = 0.f, yB1 = 0.f;
    const int row0 = (32 * wv + l) * PPAD;
    const int row1 = (32 * wv + 16 + l) * PPAD;

    #pragma unroll 1
    for (int c = 0; c < NCH; ++c) {
        // ---- cvt staged x -> bf16 A-frags (the only vmcnt wait) ----
        bf16x8 axA[4], axB[4];
        #pragma unroll
        for (int ks = 0; ks < 4; ++ks) {
            float4 u0 = xstA[ks * 2 + 0], u1 = xstA[ks * 2 + 1];
            bf16x8 f;
            f[0] = f2bf_rne(u0.x); f[1] = f2bf_rne(u0.y);
            f[2] = f2bf_rne(u0.z); f[3] = f2bf_rne(u0.w);
            f[4] = f2bf_rne(u1.x); f[5] = f2bf_rne(u1.y);
            f[6] = f2bf_rne(u1.z); f[7] = f2bf_rne(u1.w);
            axA[ks] = f;
            float4 v0 = xstB[ks * 2 + 0], v1 = xstB[ks * 2 + 1];
            bf16x8 g;
            g[0] = f2bf_rne(v0.x); g[1] = f2bf_rne(v0.y);
            g[2] = f2bf_rne(v0.z); g[3] = f2bf_rne(v0.w);
            g[4] = f2bf_rne(v1.x); g[5] = f2bf_rne(v1.y);
            g[6] = f2bf_rne(v1.z); g[7] = f2bf_rne(v1.w);
            axB[ks] = g;
        }

        // ---- issue chunk c+1's staging loads (in flight across the step loop) ----
        if (c + 1 < NCH) {
            const float* pnA = xlaneA + (size_t)(c + 1) * CH * H_N;
            const float* pnB = xlaneB + (size_t)(c + 1) * CH * H_N;
            #pragma unroll
            for (int ks = 0; ks < 4; ++ks) {
                xstA[ks * 2 + 0] = *reinterpret_cast<const float4*>(pnA + ks * 32);
                xstA[ks * 2 + 1] = *reinterpret_cast<const float4*>(pnA + ks * 32 + 4);
                xstB[ks * 2 + 0] = *reinterpret_cast<const float4*>(pnB + ks * 32);
                xstB[ks * 2 + 1] = *reinterpret_cast<const float4*>(pnB + ks * 32 + 4);
            }
        }

        __syncthreads();   // prev chunk's steps done reading pTA/pTB

        // ---- chunk GEMM, both rows; bw read once, used twice ----
        #pragma unroll
        for (int nt = 0; nt < 8; ++nt) {
            f32x4 aA, aB;
            #pragma unroll
            for (int ks = 0; ks < 4; ++ks) {
                bf16x8 bw = *reinterpret_cast<const bf16x8*>(
                    &wT[(nt * 16 + l) * WPAD + ks * 32 + q * 8]);
                aA = __builtin_amdgcn_mfma_f32_16x16x32_bf16(
                    axA[ks], bw, ks == 0 ? zero4 : aA, 0, 0, 0);
                aB = __builtin_amdgcn_mfma_f32_16x16x32_bf16(
                    axB[ks], bw, ks == 0 ? zero4 : aB, 0, 0, 0);
            }
            f32x4 oA = (f32x4){aA[0] + bv[nt], aA[1] + bv[nt],
                               aA[2] + bv[nt], aA[3] + bv[nt]};
            f32x4 oB = (f32x4){aB[0] + bv[nt], aB[1] + bv[nt],
                               aB[2] + bv[nt], aB[3] + bv[nt]};
            *reinterpret_cast<f32x4*>(&pTA[(nt * 16 + l) * PPAD + wv * 16 + q * 4]) = oA;
            *reinterpret_cast<f32x4*>(&pTB[(nt * 16 + l) * PPAD + wv * 16 + q * 4]) = oB;
        }

        __syncthreads();   // pT ready

        int tstart = 0;
        if (c == 0) {
            if (tid < 128)
                sstA[0][tid] = f2bf_rne(tanh_fast(pTA[tid * PPAD + 0]));
            else {
                int u = tid - 128;
                sstB[0][u] = f2bf_rne(tanh_fast(pTB[u * PPAD + 0]));
            }
            __syncthreads();
            tstart = 1;
            par = 0;
        }

        float pA0 = pTA[row0 + tstart];
        float pA1 = pTA[row1 + tstart];
        float pB0 = pTB[row0 + tstart];
        float pB1 = pTB[row1 + tstart];

        // ---- step loop: 1 barrier/step, TWO interleaved recurrences ----
        #pragma unroll 1
        for (int t = tstart; t < CH; ++t) {
            bf16x8 aA[4], aB[4];
            #pragma unroll
            for (int ks = 0; ks < 4; ++ks)
                aA[ks] = *reinterpret_cast<const bf16x8*>(&sstA[par][ks * 32 + q * 8]);
            #pragma unroll
            for (int ks = 0; ks < 4; ++ks)
                aB[ks] = *reinterpret_cast<const bf16x8*>(&sstB[par][ks * 32 + q * 8]);

            f32x4 accA[8];
            #pragma unroll
            for (int ks = 0; ks < 4; ++ks) {
                accA[ks]     = __builtin_amdgcn_mfma_f32_16x16x32_bf16(aA[ks], wf[0][ks], zero4, 0, 0, 0);
                accA[4 + ks] = __builtin_amdgcn_mfma_f32_16x16x32_bf16(aA[ks], wf[1][ks], zero4, 0, 0, 0);
            }
            f32x4 accB[8];
            #pragma unroll
            for (int ks = 0; ks < 4; ++ks) {
                accB[ks]     = __builtin_amdgcn_mfma_f32_16x16x32_bf16(aB[ks], wf[0][ks], zero4, 0, 0, 0);
                accB[4 + ks] = __builtin_amdgcn_mfma_f32_16x16x32_bf16(aB[ks], wf[1][ks], zero4, 0, 0, 0);
            }

            int tn = (t + 1 < CH) ? t + 1 : t;
            float npA0 = pTA[row0 + tn];
            float npA1 = pTA[row1 + tn];
            float npB0 = pTB[row0 + tn];
            float npB1 = pTB[row1 + tn];

            float zA0 = pA0 + ((accA[0][0] + accA[1][0]) + (accA[2][0] + accA[3][0]));
            float zA1 = pA1 + ((accA[4][0] + accA[5][0]) + (accA[6][0] + accA[7][0]));
            yA0 = tanh_fast(zA0);
            yA1 = tanh_fast(zA1);
            sstA[par ^ 1][32 * wv + l]      = f2bf_rne(yA0);
            sstA[par ^ 1][32 * wv + 16 + l] = f2bf_rne(yA1);

            float zB0 = pB0 + ((accB[0][0] + accB[1][0]) + (accB[2][0] + accB[3][0]));
            float zB1 = pB1 + ((accB[4][0] + accB[5][0]) + (accB[6][0] + accB[7][0]));
            yB0 = tanh_fast(zB0);
            yB1 = tanh_fast(zB1);
            sstB[par ^ 1][32 * wv + l]      = f2bf_rne(yB0);
            sstB[par ^ 1][32 * wv + 16 + l] = f2bf_rne(yB1);

            pA0 = npA0; pA1 = npA1; pB0 = npB0; pB1 = npB1;
            par ^= 1;
            __syncthreads();   // y_t visible to all waves (lgkm-only drain)
        }
    }

    if (q == 0) {
        out[r0 * H_N + 32 * wv + l]      = yA0;
        out[r0 * H_N + 32 * wv + 16 + l] = yA1;
        out[r1 * H_N + 32 * wv + l]      = yB0;
        out[r1 * H_N + 32 * wv + 16 + l] = yB1;
    }
}

extern "C" void kernel_launch(void* const* d_in, const int* in_sizes, int n_in,
                              void* d_out, int out_size, void* d_ws, size_t ws_size,
                              hipStream_t stream) {
    const float* x    = (const float*)d_in[0];  // [B][T][D] fp32
    const float* w    = (const float*)d_in[1];  // [D][H]    fp32
    const float* wst  = (const float*)d_in[2];  // [H][H]    fp32
    const float* bias = (const float*)d_in[3];  // [H]       fp32
    float* out = (float*)d_out;                 // [B][H]    fp32

    k_fused<<<128, 256, 0, stream>>>(x, w, wst, bias, out);
}

// Round 6
// 448.257 us; speedup vs baseline: 1.6711x; 1.5584x over previous
//
#include <hip/hip_runtime.h>

#define T_N 1024
#define H_N 128
#define CH   64
#define NCH (T_N / CH)     // 16
#define WPAD 136           // shorts per row of bf16 weight tiles
#define PPAD 68            // floats per row of pT

typedef __attribute__((ext_vector_type(8))) short bf16x8;
typedef __attribute__((ext_vector_type(4))) float f32x4;

__device__ __forceinline__ short f2bf_rne(float f) {
    union { float f; unsigned int i; } v; v.f = f;
    unsigned int r = v.i + 0x7FFFu + ((v.i >> 16) & 1u);
    return (short)(r >> 16);
}
__device__ __forceinline__ float tanh_fast(float x) {
    return 1.0f - 2.0f / (__expf(2.0f * x) + 1.0f);
}

// One block per batch row, EIGHT waves (512 thr). Scaling law from rounds 0-5:
// step time ~ 400cy fixed + ~17cy per per-wave MFMA -> halve per-wave work.
// Step loop: wave wv owns cols 16wv..16wv+15 (nt=wv): 4 depth-1 MFMAs,
// 1 tanh, 1 predicated ds_write_b16. GEMM phase: wave (tt=wv>>1, h=wv&1)
// computes t-tile tt x nt in {4h..4h+3}: 16 MFMAs/chunk (was 32).
// x staged in VGPRs (loads in flight across step barriers; lgkm-only drain).
__global__ __launch_bounds__(512, 1) void k_fused(const float* __restrict__ x,
                                                  const float* __restrict__ w,
                                                  const float* __restrict__ wst,
                                                  const float* __restrict__ bias,
                                                  float* __restrict__ out) {
    __shared__ __align__(16) short wT[H_N * WPAD];   // input-proj w, bf16 [n][k]
    __shared__ __align__(16) float pT[H_N * PPAD];   // proj chunk [h][t]; wsT staging at startup
    __shared__ __align__(16) short sst[2][H_N];      // state double buffer, bf16

    const int tid  = threadIdx.x;
    const int wv   = tid >> 6;       // 0..7: step cols 16wv..+15
    const int lane = tid & 63;
    const int l = lane & 15;
    const int q = lane >> 4;
    const int tt = wv >> 1;          // GEMM t-tile (x rows 16tt..+15)
    const int h  = wv & 1;           // GEMM nt half: nt in {4h..4h+3}
    const int r = blockIdx.x;
    const float* xrow = x + (size_t)r * T_N * H_N;
    const f32x4 zero4 = (f32x4){0.f, 0.f, 0.f, 0.f};

    // ---- VGPR staging: chunk 0's x rows for this lane (32 VGPRs) ----
    const float* xlane = xrow + (size_t)(tt * 16 + l) * H_N + q * 8;
    float4 xst[8];   // [ks][half]: x[16tt+l][32ks+8q .. +7]
    #pragma unroll
    for (int ks = 0; ks < 4; ++ks) {
        xst[ks * 2 + 0] = *reinterpret_cast<const float4*>(xlane + ks * 32);
        xst[ks * 2 + 1] = *reinterpret_cast<const float4*>(xlane + ks * 32 + 4);
    }

    // ---- stage wst (bf16 [n][k]) through pT's memory ----
    short* wsTs = reinterpret_cast<short*>(pT);
    for (int e = tid * 4; e < H_N * H_N; e += 2048) {
        int k = e >> 7, n = e & 127;
        float4 a4 = *reinterpret_cast<const float4*>(wst + e);
        wsTs[(n + 0) * WPAD + k] = f2bf_rne(a4.x);
        wsTs[(n + 1) * WPAD + k] = f2bf_rne(a4.y);
        wsTs[(n + 2) * WPAD + k] = f2bf_rne(a4.z);
        wsTs[(n + 3) * WPAD + k] = f2bf_rne(a4.w);
    }
    __syncthreads();

    bf16x8 wf[4];   // state-W B-frags for this wave's single nt = wv
    #pragma unroll
    for (int ks = 0; ks < 4; ++ks)
        wf[ks] = *reinterpret_cast<const bf16x8*>(
            &wsTs[(16 * wv + l) * WPAD + ks * 32 + q * 8]);
    __syncthreads();

    // ---- input-proj weights -> bf16 [n][k] LDS ----
    for (int e = tid * 4; e < H_N * H_N; e += 2048) {
        int k = e >> 7, n = e & 127;
        float4 a4 = *reinterpret_cast<const float4*>(w + e);
        wT[(n + 0) * WPAD + k] = f2bf_rne(a4.x);
        wT[(n + 1) * WPAD + k] = f2bf_rne(a4.y);
        wT[(n + 2) * WPAD + k] = f2bf_rne(a4.z);
        wT[(n + 3) * WPAD + k] = f2bf_rne(a4.w);
    }

    float bv[4];
    #pragma unroll
    for (int j = 0; j < 4; ++j) bv[j] = bias[(4 * h + j) * 16 + l];

    int par = 0;
    float y = 0.f;
    const int rowp = (16 * wv + l) * PPAD;

    #pragma unroll 1
    for (int c = 0; c < NCH; ++c) {
        // ---- cvt staged x -> bf16 A-frags (the only vmcnt wait) ----
        bf16x8 ax[4];
        #pragma unroll
        for (int ks = 0; ks < 4; ++ks) {
            float4 u0 = xst[ks * 2 + 0];
            float4 u1 = xst[ks * 2 + 1];
            bf16x8 f;
            f[0] = f2bf_rne(u0.x); f[1] = f2bf_rne(u0.y);
            f[2] = f2bf_rne(u0.z); f[3] = f2bf_rne(u0.w);
            f[4] = f2bf_rne(u1.x); f[5] = f2bf_rne(u1.y);
            f[6] = f2bf_rne(u1.z); f[7] = f2bf_rne(u1.w);
            ax[ks] = f;
        }

        // ---- issue chunk c+1's staging loads (in flight across the step loop) ----
        if (c + 1 < NCH) {
            const float* pn = xlane + (size_t)(c + 1) * CH * H_N;
            #pragma unroll
            for (int ks = 0; ks < 4; ++ks) {
                xst[ks * 2 + 0] = *reinterpret_cast<const float4*>(pn + ks * 32);
                xst[ks * 2 + 1] = *reinterpret_cast<const float4*>(pn + ks * 32 + 4);
            }
        }

        __syncthreads();   // prev chunk's steps done reading pT (lgkm-only drain)

        // ---- chunk GEMM: wave (tt,h) -> proj rows [c*64+16tt .. +15], nt 4h..4h+3 ----
        #pragma unroll
        for (int j = 0; j < 4; ++j) {
            const int nt = 4 * h + j;
            f32x4 acc;
            #pragma unroll
            for (int ks = 0; ks < 4; ++ks) {
                bf16x8 bw = *reinterpret_cast<const bf16x8*>(
                    &wT[(nt * 16 + l) * WPAD + ks * 32 + q * 8]);
                acc = __builtin_amdgcn_mfma_f32_16x16x32_bf16(
                    ax[ks], bw, ks == 0 ? zero4 : acc, 0, 0, 0);
            }
            f32x4 o = (f32x4){acc[0] + bv[j], acc[1] + bv[j],
                              acc[2] + bv[j], acc[3] + bv[j]};
            *reinterpret_cast<f32x4*>(&pT[(nt * 16 + l) * PPAD + tt * 16 + q * 4]) = o;
        }

        __syncthreads();   // pT ready

        int tstart = 0;
        if (c == 0) {
            if (tid < 128)
                sst[0][tid] = f2bf_rne(tanh_fast(pT[tid * PPAD + 0]));
            __syncthreads();
            tstart = 1;
            par = 0;
        }

        float p = pT[rowp + tstart];

        // ---- step loop: 1 barrier/step, 4 depth-1 MFMAs/wave, 1 tanh/lane ----
        #pragma unroll 1
        for (int t = tstart; t < CH; ++t) {
            bf16x8 a[4];
            #pragma unroll
            for (int ks = 0; ks < 4; ++ks)
                a[ks] = *reinterpret_cast<const bf16x8*>(&sst[par][ks * 32 + q * 8]);

            f32x4 acc[4];
            #pragma unroll
            for (int ks = 0; ks < 4; ++ks)
                acc[ks] = __builtin_amdgcn_mfma_f32_16x16x32_bf16(
                    a[ks], wf[ks], zero4, 0, 0, 0);

            int tn = (t + 1 < CH) ? t + 1 : t;
            float np = pT[rowp + tn];

            float z = p + ((acc[0][0] + acc[1][0]) + (acc[2][0] + acc[3][0]));
            y = tanh_fast(z);
            if (q == 0)
                sst[par ^ 1][16 * wv + l] = f2bf_rne(y);
            p = np;
            par ^= 1;
            __syncthreads();   // y_t visible to all waves (lgkm-only drain)
        }
    }

    if (q == 0)
        out[r * H_N + 16 * wv + l] = y;
}

extern "C" void kernel_launch(void* const* d_in, const int* in_sizes, int n_in,
                              void* d_out, int out_size, void* d_ws, size_t ws_size,
                              hipStream_t stream) {
    const float* x    = (const float*)d_in[0];  // [B][T][D] fp32
    const float* w    = (const float*)d_in[1];  // [D][H]    fp32
    const float* wst  = (const float*)d_in[2];  // [H][H]    fp32
    const float* bias = (const float*)d_in[3];  // [H]       fp32
    float* out = (float*)d_out;                 // [B][H]    fp32

    k_fused<<<256, 512, 0, stream>>>(x, w, wst, bias, out);
}

// Round 7
// 375.174 us; speedup vs baseline: 1.9967x; 1.1948x over previous
//
#include <hip/hip_runtime.h>

#define T_N 1024
#define H_N 128
#define CH   64
#define NCH (T_N / CH)     // 16
#define WPAD 136           // shorts per row of bf16 weight tiles
#define PPAD 68            // floats per row of pT

typedef __attribute__((ext_vector_type(8))) short bf16x8;
typedef __attribute__((ext_vector_type(4))) float f32x4;

__device__ __forceinline__ short f2bf_rne(float f) {
    union { float f; unsigned int i; } v; v.f = f;
    unsigned int r = v.i + 0x7FFFu + ((v.i >> 16) & 1u);
    return (short)(r >> 16);
}

// One block per batch row, EIGHT waves (512 thr) — round-6 structure (best:
// 318ns/step) with the serial chain trimmed:
//  - tanh via v_rcp (was IEEE div: ~10-op v_div_* sequence ON the chain)
//  - state cvt via one v_cvt_pk_bf16_f32 (was 4-op f2bf)
//  - step pair-unrolled sst0->sst1->sst0: all LDS addrs static immediates,
//    no par xor/addr math
//  - p folded into MFMA C-operand (broadcast movs hide under ds_read wait)
//  - uniform 64-step chunks from zero state (step 0: tanh(p0 + W*0) == state0)
//    -> no c==0 special case, even trip count, chunk-top barrier dropped
__global__ __launch_bounds__(512, 1) void k_fused(const float* __restrict__ x,
                                                  const float* __restrict__ w,
                                                  const float* __restrict__ wst,
                                                  const float* __restrict__ bias,
                                                  float* __restrict__ out) {
    __shared__ __align__(16) short wT[H_N * WPAD];   // input-proj w, bf16 [n][k]
    __shared__ __align__(16) float pT[H_N * PPAD];   // proj chunk [h][t]; wsT staging at startup
    __shared__ __align__(16) short sst[2][H_N];      // state double buffer, bf16

    const int tid  = threadIdx.x;
    const int wv   = tid >> 6;       // 0..7: step cols 16wv..+15
    const int lane = tid & 63;
    const int l = lane & 15;
    const int q = lane >> 4;
    const int tt = wv >> 1;          // GEMM t-tile (x rows 16tt..+15)
    const int h  = wv & 1;           // GEMM nt half: nt in {4h..4h+3}
    const int r = blockIdx.x;
    const float* xrow = x + (size_t)r * T_N * H_N;
    const f32x4 zero4 = (f32x4){0.f, 0.f, 0.f, 0.f};

    // ---- VGPR staging: chunk 0's x rows for this lane (32 VGPRs) ----
    const float* xlane = xrow + (size_t)(tt * 16 + l) * H_N + q * 8;
    float4 xst[8];   // [ks][half]: x[16tt+l][32ks+8q .. +7]
    #pragma unroll
    for (int ks = 0; ks < 4; ++ks) {
        xst[ks * 2 + 0] = *reinterpret_cast<const float4*>(xlane + ks * 32);
        xst[ks * 2 + 1] = *reinterpret_cast<const float4*>(xlane + ks * 32 + 4);
    }

    // ---- stage wst (bf16 [n][k]) through pT's memory ----
    short* wsTs = reinterpret_cast<short*>(pT);
    for (int e = tid * 4; e < H_N * H_N; e += 2048) {
        int k = e >> 7, n = e & 127;
        float4 a4 = *reinterpret_cast<const float4*>(wst + e);
        wsTs[(n + 0) * WPAD + k] = f2bf_rne(a4.x);
        wsTs[(n + 1) * WPAD + k] = f2bf_rne(a4.y);
        wsTs[(n + 2) * WPAD + k] = f2bf_rne(a4.z);
        wsTs[(n + 3) * WPAD + k] = f2bf_rne(a4.w);
    }
    __syncthreads();

    bf16x8 wf[4];   // state-W B-frags for this wave's single nt = wv
    #pragma unroll
    for (int ks = 0; ks < 4; ++ks)
        wf[ks] = *reinterpret_cast<const bf16x8*>(
            &wsTs[(16 * wv + l) * WPAD + ks * 32 + q * 8]);

    // zero state (bf16 +0.0): step 0 then computes tanh(p0 + W*0) = state0
    if (tid < 128) sst[0][tid] = 0;

    // ---- input-proj weights -> bf16 [n][k] LDS ----
    for (int e = tid * 4; e < H_N * H_N; e += 2048) {
        int k = e >> 7, n = e & 127;
        float4 a4 = *reinterpret_cast<const float4*>(w + e);
        wT[(n + 0) * WPAD + k] = f2bf_rne(a4.x);
        wT[(n + 1) * WPAD + k] = f2bf_rne(a4.y);
        wT[(n + 2) * WPAD + k] = f2bf_rne(a4.z);
        wT[(n + 3) * WPAD + k] = f2bf_rne(a4.w);
    }

    float bv[4];
    #pragma unroll
    for (int j = 0; j < 4; ++j) bv[j] = bias[(4 * h + j) * 16 + l];

    __syncthreads();   // wf gathered, sst zeroed, wT staged -> safe to overwrite pT

    float y = 0.f;
    float p = 0.f;
    const int rowp = (16 * wv + l) * PPAD;

    // one recurrence step: read srd state, matvec, tanh, write swr state
    auto step = [&](const short* srd, short* swr, int t) {
        bf16x8 a0 = *reinterpret_cast<const bf16x8*>(&srd[ 0 + q * 8]);
        bf16x8 a1 = *reinterpret_cast<const bf16x8*>(&srd[32 + q * 8]);
        bf16x8 a2 = *reinterpret_cast<const bf16x8*>(&srd[64 + q * 8]);
        bf16x8 a3 = *reinterpret_cast<const bf16x8*>(&srd[96 + q * 8]);
        int tn = (t + 1 < CH) ? t + 1 : t;
        float np = pT[rowp + tn];
        f32x4 c4 = (f32x4){p, p, p, p};   // p prefetched last step: movs hide under ds_read
        f32x4 x0 = __builtin_amdgcn_mfma_f32_16x16x32_bf16(a0, wf[0], c4, 0, 0, 0);
        f32x4 x1 = __builtin_amdgcn_mfma_f32_16x16x32_bf16(a1, wf[1], zero4, 0, 0, 0);
        f32x4 x2 = __builtin_amdgcn_mfma_f32_16x16x32_bf16(a2, wf[2], zero4, 0, 0, 0);
        f32x4 x3 = __builtin_amdgcn_mfma_f32_16x16x32_bf16(a3, wf[3], zero4, 0, 0, 0);
        float z = (x0[0] + x1[0]) + (x2[0] + x3[0]);   // includes p via C-init
        float e = __expf(2.0f * z);
        y = __builtin_fmaf(-2.0f, __builtin_amdgcn_rcpf(e + 1.0f), 1.0f);
        unsigned int pk;
        asm("v_cvt_pk_bf16_f32 %0, %1, %2" : "=v"(pk) : "v"(y), "v"(y));
        if (q == 0)
            swr[16 * wv + l] = (short)pk;
        p = np;
        __syncthreads();   // y_t visible to all waves (lgkm-only drain)
    };

    #pragma unroll 1
    for (int c = 0; c < NCH; ++c) {
        // ---- cvt staged x -> bf16 A-frags (the only vmcnt wait) ----
        bf16x8 ax[4];
        #pragma unroll
        for (int ks = 0; ks < 4; ++ks) {
            float4 u0 = xst[ks * 2 + 0];
            float4 u1 = xst[ks * 2 + 1];
            bf16x8 f;
            f[0] = f2bf_rne(u0.x); f[1] = f2bf_rne(u0.y);
            f[2] = f2bf_rne(u0.z); f[3] = f2bf_rne(u0.w);
            f[4] = f2bf_rne(u1.x); f[5] = f2bf_rne(u1.y);
            f[6] = f2bf_rne(u1.z); f[7] = f2bf_rne(u1.w);
            ax[ks] = f;
        }

        // ---- issue chunk c+1's staging loads (in flight across the step loop) ----
        if (c + 1 < NCH) {
            const float* pn = xlane + (size_t)(c + 1) * CH * H_N;
            #pragma unroll
            for (int ks = 0; ks < 4; ++ks) {
                xst[ks * 2 + 0] = *reinterpret_cast<const float4*>(pn + ks * 32);
                xst[ks * 2 + 1] = *reinterpret_cast<const float4*>(pn + ks * 32 + 4);
            }
        }

        // NOTE: no barrier here — the previous chunk's final step barrier
        // already ordered all pT reads before these writes.

        // ---- chunk GEMM: wave (tt,h) -> proj rows [c*64+16tt .. +15], nt 4h..4h+3 ----
        #pragma unroll
        for (int j = 0; j < 4; ++j) {
            const int nt = 4 * h + j;
            f32x4 cb = (f32x4){bv[j], bv[j], bv[j], bv[j]};
            f32x4 acc;
            #pragma unroll
            for (int ks = 0; ks < 4; ++ks) {
                bf16x8 bw = *reinterpret_cast<const bf16x8*>(
                    &wT[(nt * 16 + l) * WPAD + ks * 32 + q * 8]);
                acc = __builtin_amdgcn_mfma_f32_16x16x32_bf16(
                    ax[ks], bw, ks == 0 ? cb : acc, 0, 0, 0);
            }
            *reinterpret_cast<f32x4*>(&pT[(nt * 16 + l) * PPAD + tt * 16 + q * 4]) = acc;
        }

        __syncthreads();   // pT ready

        p = pT[rowp];      // first step's proj value

        // ---- step loop: 64 uniform steps, pair-unrolled, static LDS addrs ----
        #pragma unroll 1
        for (int t = 0; t < CH; t += 2) {
            step(sst[0], sst[1], t);
            step(sst[1], sst[0], t + 1);
        }
    }

    if (q == 0)
        out[r * H_N + 16 * wv + l] = y;
}

extern "C" void kernel_launch(void* const* d_in, const int* in_sizes, int n_in,
                              void* d_out, int out_size, void* d_ws, size_t ws_size,
                              hipStream_t stream) {
    const float* x    = (const float*)d_in[0];  // [B][T][D] fp32
    const float* w    = (const float*)d_in[1];  // [D][H]    fp32
    const float* wst  = (const float*)d_in[2];  // [H][H]    fp32
    const float* bias = (const float*)d_in[3];  // [H]       fp32
    float* out = (float*)d_out;                 // [B][H]    fp32

    k_fused<<<256, 512, 0, stream>>>(x, w, wst, bias, out);
}

// Round 8
// 374.465 us; speedup vs baseline: 2.0004x; 1.0019x over previous
//
#include <hip/hip_runtime.h>

#define T_N 1024
#define H_N 128
#define CH   64
#define NCH (T_N / CH)     // 16
#define WPAD 136           // shorts per row of bf16 weight tiles
#define PPAD 68            // floats per row of pT

typedef __attribute__((ext_vector_type(8))) short bf16x8;
typedef __attribute__((ext_vector_type(4))) float f32x4;

__device__ __forceinline__ short f2bf_rne(float f) {
    union { float f; unsigned int i; } v; v.f = f;
    unsigned int r = v.i + 0x7FFFu + ((v.i >> 16) & 1u);
    return (short)(r >> 16);
}

// One block per batch row, EIGHT waves (512 thr). Round-7 structure (252us)
// with the step loop de-cluttered:
//  - 8-step sub-unroll + p-REGISTER-BLOCK: per 8 steps, 2x ds_read_b128 pull
//    8 proj values into regs (replaces 8 scalar pT reads + 8 tn-cndmask +
//    8 addr adds riding the chain). All p indices compile-time constants.
//  - step body now: 4 ds_read_b128 (state), 4 depth-1 MFMA (p folded in C of
//    MFMA0, movs off-chain), add-tree + rcp-tanh + cvt_pk, 1 predicated
//    ds_write_b16, 1 barrier.
//  - uniform 64-step chunks from zero state; no chunk-top barrier (last step
//    barrier orders pT reads vs next GEMM writes).
__global__ __launch_bounds__(512, 1) void k_fused(const float* __restrict__ x,
                                                  const float* __restrict__ w,
                                                  const float* __restrict__ wst,
                                                  const float* __restrict__ bias,
                                                  float* __restrict__ out) {
    __shared__ __align__(16) short wT[H_N * WPAD];   // input-proj w, bf16 [n][k]
    __shared__ __align__(16) float pT[H_N * PPAD];   // proj chunk [h][t]; wsT staging at startup
    __shared__ __align__(16) short sst[2][H_N];      // state double buffer, bf16

    const int tid  = threadIdx.x;
    const int wv   = tid >> 6;       // 0..7: step cols 16wv..+15
    const int lane = tid & 63;
    const int l = lane & 15;
    const int q = lane >> 4;
    const int tt = wv >> 1;          // GEMM t-tile (x rows 16tt..+15)
    const int h  = wv & 1;           // GEMM nt half: nt in {4h..4h+3}
    const int r = blockIdx.x;
    const float* xrow = x + (size_t)r * T_N * H_N;
    const f32x4 zero4 = (f32x4){0.f, 0.f, 0.f, 0.f};

    // ---- VGPR staging: chunk 0's x rows for this lane (32 VGPRs) ----
    const float* xlane = xrow + (size_t)(tt * 16 + l) * H_N + q * 8;
    float4 xst[8];   // [ks][half]: x[16tt+l][32ks+8q .. +7]
    #pragma unroll
    for (int ks = 0; ks < 4; ++ks) {
        xst[ks * 2 + 0] = *reinterpret_cast<const float4*>(xlane + ks * 32);
        xst[ks * 2 + 1] = *reinterpret_cast<const float4*>(xlane + ks * 32 + 4);
    }

    // ---- stage wst (bf16 [n][k]) through pT's memory ----
    short* wsTs = reinterpret_cast<short*>(pT);
    for (int e = tid * 4; e < H_N * H_N; e += 2048) {
        int k = e >> 7, n = e & 127;
        float4 a4 = *reinterpret_cast<const float4*>(wst + e);
        wsTs[(n + 0) * WPAD + k] = f2bf_rne(a4.x);
        wsTs[(n + 1) * WPAD + k] = f2bf_rne(a4.y);
        wsTs[(n + 2) * WPAD + k] = f2bf_rne(a4.z);
        wsTs[(n + 3) * WPAD + k] = f2bf_rne(a4.w);
    }
    __syncthreads();

    bf16x8 wf[4];   // state-W B-frags for this wave's single nt = wv
    #pragma unroll
    for (int ks = 0; ks < 4; ++ks)
        wf[ks] = *reinterpret_cast<const bf16x8*>(
            &wsTs[(16 * wv + l) * WPAD + ks * 32 + q * 8]);

    // zero state (bf16 +0.0): step 0 then computes tanh(p0 + W*0) = state0
    if (tid < 128) sst[0][tid] = 0;

    // ---- input-proj weights -> bf16 [n][k] LDS ----
    for (int e = tid * 4; e < H_N * H_N; e += 2048) {
        int k = e >> 7, n = e & 127;
        float4 a4 = *reinterpret_cast<const float4*>(w + e);
        wT[(n + 0) * WPAD + k] = f2bf_rne(a4.x);
        wT[(n + 1) * WPAD + k] = f2bf_rne(a4.y);
        wT[(n + 2) * WPAD + k] = f2bf_rne(a4.z);
        wT[(n + 3) * WPAD + k] = f2bf_rne(a4.w);
    }

    float bv[4];
    #pragma unroll
    for (int j = 0; j < 4; ++j) bv[j] = bias[(4 * h + j) * 16 + l];

    __syncthreads();   // wf gathered, sst zeroed, wT staged -> safe to overwrite pT

    float y = 0.f;
    const int rowp = (16 * wv + l) * PPAD;

    // one recurrence step: read srd state, matvec (+pv via C), tanh, write swr
    auto step = [&](const short* srd, short* swr, float pv) {
        bf16x8 a0 = *reinterpret_cast<const bf16x8*>(&srd[ 0 + q * 8]);
        bf16x8 a1 = *reinterpret_cast<const bf16x8*>(&srd[32 + q * 8]);
        bf16x8 a2 = *reinterpret_cast<const bf16x8*>(&srd[64 + q * 8]);
        bf16x8 a3 = *reinterpret_cast<const bf16x8*>(&srd[96 + q * 8]);
        f32x4 c4 = (f32x4){pv, pv, pv, pv};   // pv known 8 steps early: movs off-chain
        f32x4 x0 = __builtin_amdgcn_mfma_f32_16x16x32_bf16(a0, wf[0], c4, 0, 0, 0);
        f32x4 x1 = __builtin_amdgcn_mfma_f32_16x16x32_bf16(a1, wf[1], zero4, 0, 0, 0);
        f32x4 x2 = __builtin_amdgcn_mfma_f32_16x16x32_bf16(a2, wf[2], zero4, 0, 0, 0);
        f32x4 x3 = __builtin_amdgcn_mfma_f32_16x16x32_bf16(a3, wf[3], zero4, 0, 0, 0);
        float z = (x0[0] + x1[0]) + (x2[0] + x3[0]);   // includes pv via C-init
        float e = __expf(2.0f * z);
        y = __builtin_fmaf(-2.0f, __builtin_amdgcn_rcpf(e + 1.0f), 1.0f);
        unsigned int pk;
        asm("v_cvt_pk_bf16_f32 %0, %1, %2" : "=v"(pk) : "v"(y), "v"(y));
        if (q == 0)
            swr[16 * wv + l] = (short)pk;
        __syncthreads();   // y_t visible to all waves (lgkm-only drain)
    };

    #pragma unroll 1
    for (int c = 0; c < NCH; ++c) {
        // ---- cvt staged x -> bf16 A-frags (the only vmcnt wait) ----
        bf16x8 ax[4];
        #pragma unroll
        for (int ks = 0; ks < 4; ++ks) {
            float4 u0 = xst[ks * 2 + 0];
            float4 u1 = xst[ks * 2 + 1];
            bf16x8 f;
            f[0] = f2bf_rne(u0.x); f[1] = f2bf_rne(u0.y);
            f[2] = f2bf_rne(u0.z); f[3] = f2bf_rne(u0.w);
            f[4] = f2bf_rne(u1.x); f[5] = f2bf_rne(u1.y);
            f[6] = f2bf_rne(u1.z); f[7] = f2bf_rne(u1.w);
            ax[ks] = f;
        }

        // ---- issue chunk c+1's staging loads (in flight across the step loop) ----
        if (c + 1 < NCH) {
            const float* pn = xlane + (size_t)(c + 1) * CH * H_N;
            #pragma unroll
            for (int ks = 0; ks < 4; ++ks) {
                xst[ks * 2 + 0] = *reinterpret_cast<const float4*>(pn + ks * 32);
                xst[ks * 2 + 1] = *reinterpret_cast<const float4*>(pn + ks * 32 + 4);
            }
        }

        // NOTE: no barrier here — the previous chunk's final step barrier
        // already ordered all pT reads before these writes.

        // ---- chunk GEMM: wave (tt,h) -> proj rows [c*64+16tt .. +15], nt 4h..4h+3 ----
        #pragma unroll
        for (int j = 0; j < 4; ++j) {
            const int nt = 4 * h + j;
            f32x4 cb = (f32x4){bv[j], bv[j], bv[j], bv[j]};
            f32x4 acc;
            #pragma unroll
            for (int ks = 0; ks < 4; ++ks) {
                bf16x8 bw = *reinterpret_cast<const bf16x8*>(
                    &wT[(nt * 16 + l) * WPAD + ks * 32 + q * 8]);
                acc = __builtin_amdgcn_mfma_f32_16x16x32_bf16(
                    ax[ks], bw, ks == 0 ? cb : acc, 0, 0, 0);
            }
            *reinterpret_cast<f32x4*>(&pT[(nt * 16 + l) * PPAD + tt * 16 + q * 4]) = acc;
        }

        __syncthreads();   // pT ready

        // ---- step loop: 8 sub-blocks x 8 steps; p-block in regs, static idx ----
        #pragma unroll 1
        for (int s = 0; s < CH / 8; ++s) {
            float4 pb0 = *reinterpret_cast<const float4*>(&pT[rowp + 8 * s]);
            float4 pb1 = *reinterpret_cast<const float4*>(&pT[rowp + 8 * s + 4]);
            step(sst[0], sst[1], pb0.x);
            step(sst[1], sst[0], pb0.y);
            step(sst[0], sst[1], pb0.z);
            step(sst[1], sst[0], pb0.w);
            step(sst[0], sst[1], pb1.x);
            step(sst[1], sst[0], pb1.y);
            step(sst[0], sst[1], pb1.z);
            step(sst[1], sst[0], pb1.w);
        }
    }

    if (q == 0)
        out[r * H_N + 16 * wv + l] = y;
}

extern "C" void kernel_launch(void* const* d_in, const int* in_sizes, int n_in,
                              void* d_out, int out_size, void* d_ws, size_t ws_size,
                              hipStream_t stream) {
    const float* x    = (const float*)d_in[0];  // [B][T][D] fp32
    const float* w    = (const float*)d_in[1];  // [D][H]    fp32
    const float* wst  = (const float*)d_in[2];  // [H][H]    fp32
    const float* bias = (const float*)d_in[3];  // [H]       fp32
    float* out = (float*)d_out;                 // [B][H]    fp32

    k_fused<<<256, 512, 0, stream>>>(x, w, wst, bias, out);
}